// Round 2
// baseline (203.476 us; speedup 1.0000x reference)
//
#include <hip/hip_runtime.h>

// Problem constants (from reference setup_inputs):
//   q,k,v: [B=8, d=768, N=6144] fp32; head_dim=32, kernel_size=3
//   h = 24 heads, g = 2048 windows; window elem j of window gg at n = j*2048 + gg
// Output layout (x.transpose(0,2,1,3,4).reshape(B,N,d) flattens to):
//   out_flat[b][gg][hh][kq][dd], contiguous [8, 2048, 24, 3, 32]
constexpr int CB = 8;
constexpr int CD = 768;
constexpr int CN = 6144;
constexpr int HD = 32;
constexpr int KS = 3;
constexpr int CH = CD / HD;   // 24
constexpr int CG = CN / KS;   // 2048

__global__ __launch_bounds__(256) void dilate_attn_kernel(
    const float* __restrict__ q, const float* __restrict__ k,
    const float* __restrict__ v, float* __restrict__ out) {
  const int idx = blockIdx.x * 256 + threadIdx.x;  // (b, hh, gg), gg fastest
  const int gg = idx & (CG - 1);
  const int bh = idx >> 11;        // b*24 + hh
  const int hh = bh % CH;
  const int b  = bh / CH;

  const size_t inbase = ((size_t)b * CD + (size_t)hh * HD) * (size_t)CN + (size_t)gg;
  const float* qb = q + inbase;
  const float* kb = k + inbase;
  const float* vb = v + inbase;

  // ---- scores: s[kq][kj] = sum_dd q[kq*G+gg + dd*N] * k[kj*G+gg + dd*N]
  float s00 = 0.f, s01 = 0.f, s02 = 0.f;
  float s10 = 0.f, s11 = 0.f, s12 = 0.f;
  float s20 = 0.f, s21 = 0.f, s22 = 0.f;
  #pragma unroll 8
  for (int dd = 0; dd < HD; ++dd) {
    const float* qp = qb + (size_t)dd * CN;
    const float* kp = kb + (size_t)dd * CN;
    const float q0 = qp[0], q1 = qp[CG], q2 = qp[2 * CG];
    const float k0 = kp[0], k1 = kp[CG], k2 = kp[2 * CG];
    s00 = fmaf(q0, k0, s00); s01 = fmaf(q0, k1, s01); s02 = fmaf(q0, k2, s02);
    s10 = fmaf(q1, k0, s10); s11 = fmaf(q1, k1, s11); s12 = fmaf(q1, k2, s12);
    s20 = fmaf(q2, k0, s20); s21 = fmaf(q2, k1, s21); s22 = fmaf(q2, k2, s22);
  }

  const float scale = 0.17677669529663687f;  // 32^-0.5
  s00 *= scale; s01 *= scale; s02 *= scale;
  s10 *= scale; s11 *= scale; s12 *= scale;
  s20 *= scale; s21 *= scale; s22 *= scale;

  // ---- softmax over kj (last axis), per row kq
  float m0 = fmaxf(fmaxf(s00, s01), s02);
  float m1 = fmaxf(fmaxf(s10, s11), s12);
  float m2 = fmaxf(fmaxf(s20, s21), s22);
  float e00 = __expf(s00 - m0), e01 = __expf(s01 - m0), e02 = __expf(s02 - m0);
  float e10 = __expf(s10 - m1), e11 = __expf(s11 - m1), e12 = __expf(s12 - m1);
  float e20 = __expf(s20 - m2), e21 = __expf(s21 - m2), e22 = __expf(s22 - m2);
  const float r0 = 1.f / (e00 + e01 + e02);
  const float r1 = 1.f / (e10 + e11 + e12);
  const float r2 = 1.f / (e20 + e21 + e22);
  const float p00 = e00 * r0, p01 = e01 * r0, p02 = e02 * r0;
  const float p10 = e10 * r1, p11 = e11 * r1, p12 = e12 * r1;
  const float p20 = e20 * r2, p21 = e21 * r2, p22 = e22 * r2;

  // ---- PV + write: out_flat[b][gg][hh][kq][dd], contiguous [8,2048,24,3,32]
  float* ob = out + ((size_t)b * CG + (size_t)gg) * (size_t)(CH * KS * HD)
                  + (size_t)hh * (KS * HD);
  #pragma unroll
  for (int dd4 = 0; dd4 < HD / 4; ++dd4) {
    float o0[4], o1[4], o2[4];
    #pragma unroll
    for (int l = 0; l < 4; ++l) {
      const int dd = dd4 * 4 + l;
      const float* vp = vb + (size_t)dd * CN;
      const float v0 = vp[0], v1 = vp[CG], v2 = vp[2 * CG];
      o0[l] = p00 * v0 + p01 * v1 + p02 * v2;
      o1[l] = p10 * v0 + p11 * v1 + p12 * v2;
      o2[l] = p20 * v0 + p21 * v1 + p22 * v2;
    }
    *reinterpret_cast<float4*>(ob + 0 * HD + dd4 * 4) = make_float4(o0[0], o0[1], o0[2], o0[3]);
    *reinterpret_cast<float4*>(ob + 1 * HD + dd4 * 4) = make_float4(o1[0], o1[1], o1[2], o1[3]);
    *reinterpret_cast<float4*>(ob + 2 * HD + dd4 * 4) = make_float4(o2[0], o2[1], o2[2], o2[3]);
  }
}

extern "C" void kernel_launch(void* const* d_in, const int* in_sizes, int n_in,
                              void* d_out, int out_size, void* d_ws, size_t ws_size,
                              hipStream_t stream) {
  const float* q = (const float*)d_in[0];
  const float* k = (const float*)d_in[1];
  const float* v = (const float*)d_in[2];
  float* out = (float*)d_out;

  const int total = CB * CH * CG;            // 393216 threads, one per (b,h,gg)
  const int blocks = total / 256;            // 1536
  dilate_attn_kernel<<<blocks, 256, 0, stream>>>(q, k, v, out);
}